// Round 1
// baseline (3790.366 us; speedup 1.0000x reference)
//
#include <hip/hip_runtime.h>

#define NN 100000
#define EM 1600000
#define EA 200000
#define ET (EM + EA)

// ws layout (floats):
//   deg[NN] | cnt[NN] | efsum[4*NN] | agg[128*NN] | norm[NN] | Wt[2*128*128]
// deg..agg (134*NN floats) are memset to 0 each call.
#define OFF_DEG   0
#define OFF_CNT   (NN)
#define OFF_EFSUM (2*NN)
#define OFF_AGG   (6*NN)
#define OFF_NORM  (134*NN)
#define OFF_WT    (135*NN)

__global__ __launch_bounds__(256) void k_count(
    const int* __restrict__ srcE, const int* __restrict__ dstE,
    const int* __restrict__ dstA, const float* __restrict__ ef,
    float* __restrict__ deg, float* __restrict__ cnt, float* __restrict__ efsum) {
  int e = blockIdx.x * 256 + threadIdx.x;
  if (e < EM) {
    int s = srcE[e], d = dstE[e];
    unsafeAtomicAdd(&deg[s], 1.0f);
    unsafeAtomicAdd(&cnt[d], 1.0f);
    float4 f = ((const float4*)ef)[e];
    unsafeAtomicAdd(&efsum[d * 4 + 0], f.x);
    unsafeAtomicAdd(&efsum[d * 4 + 1], f.y);
    unsafeAtomicAdd(&efsum[d * 4 + 2], f.z);
    unsafeAtomicAdd(&efsum[d * 4 + 3], f.w);
  } else if (e < ET) {
    int d = dstA[e - EM];
    unsafeAtomicAdd(&cnt[d], 1.0f);
  }
}

__global__ __launch_bounds__(256) void k_norm_wt(
    const float* __restrict__ deg, float* __restrict__ norm,
    const float* __restrict__ Wmsg, const float* __restrict__ Wskip,
    float* __restrict__ Wt) {
  int i = blockIdx.x * 256 + threadIdx.x;
  if (i < NN) {
    float dg = deg[i];
    norm[i] = dg > 0.0f ? rsqrtf(dg) : 0.0f;
  }
  if (i < 128 * 128) {
    int j = i >> 7, k = i & 127;
    // Wt[k][j] = Wmsg[j][k]; second half for Wskip
    Wt[k * 128 + j]         = Wmsg[j * 128 + k];
    Wt[16384 + k * 128 + j] = Wskip[j * 128 + k];
  }
}

// 32 threads per edge, float4 per lane: agg[d] += att * norm[s] * feats[s]
__global__ __launch_bounds__(256) void k_scatter(
    const int* __restrict__ srcE, const int* __restrict__ dstE,
    const int* __restrict__ srcA, const int* __restrict__ dstA,
    const float* __restrict__ ef, const float* __restrict__ Watt,
    const float* __restrict__ batt,
    const float* __restrict__ feats, const float* __restrict__ norm,
    float* __restrict__ agg) {
  int gt = blockIdx.x * 256 + threadIdx.x;
  int e = gt >> 5;       // edge index
  int c = gt & 31;       // float4 chunk within the 128-wide row
  if (e >= ET) return;
  int s, d;
  float att;
  if (e < EM) {
    s = srcE[e];
    d = dstE[e];
    float4 f = ((const float4*)ef)[e];
    float z = f.x * Watt[0] + f.y * Watt[1] + f.z * Watt[2] + f.w * Watt[3] + batt[0];
    att = 1.0f / (1.0f + __expf(-z));
  } else {
    int ea = e - EM;
    s = srcA[ea];
    d = dstA[ea];
    att = 1.0f / (1.0f + __expf(-batt[0]));
  }
  float nm = norm[s] * att;
  float4 h = ((const float4*)feats)[s * 32 + c];
  float* ap = agg + d * 128 + c * 4;
  unsafeAtomicAdd(ap + 0, nm * h.x);
  unsafeAtomicAdd(ap + 1, nm * h.y);
  unsafeAtomicAdd(ap + 2, nm * h.z);
  unsafeAtomicAdd(ap + 3, nm * h.w);
}

// out[n][j] = sum_k x[n][k] * Wt_cat[k][j] + b_msg[j] + b_skip[j]
//   x[n][k]     = (agg[n][k] + W_edge[k]·efsum[n] + cnt[n]*(b_edge[k] + nm*feats[n][k])) * nm   (k < 128)
//   x[n][128+k] = feats[n][k]
// Tile: 32 nodes x 128 cols per block; 256 threads; 4n x 4j per thread.
__global__ __launch_bounds__(256) void k_out(
    const float* __restrict__ feats, const float* __restrict__ agg,
    const float* __restrict__ norm, const float* __restrict__ cnt,
    const float* __restrict__ efsum, const float* __restrict__ Wedge,
    const float* __restrict__ bedge, const float* __restrict__ Wt,
    const float* __restrict__ bmsg, const float* __restrict__ bskip,
    float* __restrict__ out) {
  __shared__ float x[256 * 33];  // [k][nn], stride 33 to spread banks
  int n0 = blockIdx.x * 32;
  int tid = threadIdx.x;

  // staging: 32 nodes x 64 float4-chunks = 2048 iterations
  for (int i = tid; i < 2048; i += 256) {
    int nn = i >> 6, q = i & 63;
    int n = n0 + nn;
    float4 v;
    if (q < 32) {
      int k = q * 4;
      float4 a  = ((const float4*)agg)[n * 32 + q];
      float4 f  = ((const float4*)feats)[n * 32 + q];
      float4 be = ((const float4*)bedge)[q];
      float4 es = ((const float4*)efsum)[n];
      float  cs = cnt[n];
      float  nm = norm[n];
      float4 w0 = ((const float4*)Wedge)[k + 0];
      float4 w1 = ((const float4*)Wedge)[k + 1];
      float4 w2 = ((const float4*)Wedge)[k + 2];
      float4 w3 = ((const float4*)Wedge)[k + 3];
      v.x = (a.x + w0.x*es.x + w0.y*es.y + w0.z*es.z + w0.w*es.w + cs*(be.x + nm*f.x)) * nm;
      v.y = (a.y + w1.x*es.x + w1.y*es.y + w1.z*es.z + w1.w*es.w + cs*(be.y + nm*f.y)) * nm;
      v.z = (a.z + w2.x*es.x + w2.y*es.y + w2.z*es.z + w2.w*es.w + cs*(be.z + nm*f.z)) * nm;
      v.w = (a.w + w3.x*es.x + w3.y*es.y + w3.z*es.z + w3.w*es.w + cs*(be.w + nm*f.w)) * nm;
    } else {
      v = ((const float4*)feats)[n * 32 + (q - 32)];
    }
    int k = q * 4;
    x[(k + 0) * 33 + nn] = v.x;
    x[(k + 1) * 33 + nn] = v.y;
    x[(k + 2) * 33 + nn] = v.z;
    x[(k + 3) * 33 + nn] = v.w;
  }
  __syncthreads();

  int jg = tid & 31;   // j block: columns 4*jg .. 4*jg+3
  int ng = tid >> 5;   // n block: rows 4*ng .. 4*ng+3
  float acc[4][4] = {{0.f}};

#pragma unroll 4
  for (int k = 0; k < 256; ++k) {
    float4 w = ((const float4*)(Wt + k * 128))[jg];
    float x0 = x[k * 33 + 4 * ng + 0];
    float x1 = x[k * 33 + 4 * ng + 1];
    float x2 = x[k * 33 + 4 * ng + 2];
    float x3 = x[k * 33 + 4 * ng + 3];
    acc[0][0] += x0 * w.x; acc[0][1] += x0 * w.y; acc[0][2] += x0 * w.z; acc[0][3] += x0 * w.w;
    acc[1][0] += x1 * w.x; acc[1][1] += x1 * w.y; acc[1][2] += x1 * w.z; acc[1][3] += x1 * w.w;
    acc[2][0] += x2 * w.x; acc[2][1] += x2 * w.y; acc[2][2] += x2 * w.z; acc[2][3] += x2 * w.w;
    acc[3][0] += x3 * w.x; acc[3][1] += x3 * w.y; acc[3][2] += x3 * w.z; acc[3][3] += x3 * w.w;
  }

  float4 bm = ((const float4*)bmsg)[jg];
  float4 bs = ((const float4*)bskip)[jg];
  float b0 = bm.x + bs.x, b1 = bm.y + bs.y, b2 = bm.z + bs.z, b3 = bm.w + bs.w;
#pragma unroll
  for (int i = 0; i < 4; ++i) {
    int n = n0 + 4 * ng + i;
    float4 o = make_float4(acc[i][0] + b0, acc[i][1] + b1, acc[i][2] + b2, acc[i][3] + b3);
    ((float4*)out)[n * 32 + jg] = o;
  }
}

extern "C" void kernel_launch(void* const* d_in, const int* in_sizes, int n_in,
                              void* d_out, int out_size, void* d_ws, size_t ws_size,
                              hipStream_t stream) {
  const float* feats  = (const float*)d_in[0];
  const float* ef     = (const float*)d_in[1];
  const int*   srcE   = (const int*)d_in[2];
  const int*   dstE   = (const int*)d_in[3];
  const int*   srcA   = (const int*)d_in[4];
  const int*   dstA   = (const int*)d_in[5];
  const float* Wskip  = (const float*)d_in[6];
  const float* bskip  = (const float*)d_in[7];
  const float* Wmsg   = (const float*)d_in[8];
  const float* bmsg   = (const float*)d_in[9];
  const float* Wedge  = (const float*)d_in[10];
  const float* bedge  = (const float*)d_in[11];
  const float* Watt   = (const float*)d_in[12];
  const float* batt   = (const float*)d_in[13];
  float* out = (float*)d_out;
  float* ws  = (float*)d_ws;

  float* deg   = ws + OFF_DEG;
  float* cnt   = ws + OFF_CNT;
  float* efsum = ws + OFF_EFSUM;
  float* agg   = ws + OFF_AGG;
  float* norm  = ws + OFF_NORM;
  float* Wt    = ws + OFF_WT;

  // zero deg/cnt/efsum/agg in one contiguous memset
  hipMemsetAsync(ws, 0, (size_t)(134 * NN) * sizeof(float), stream);

  k_count<<<(ET + 255) / 256, 256, 0, stream>>>(srcE, dstE, dstA, ef, deg, cnt, efsum);

  k_norm_wt<<<(NN + 255) / 256, 256, 0, stream>>>(deg, norm, Wmsg, Wskip, Wt);

  {
    long long threads = (long long)ET * 32;
    int blocks = (int)((threads + 255) / 256);
    k_scatter<<<blocks, 256, 0, stream>>>(srcE, dstE, srcA, dstA, ef, Watt, batt,
                                          feats, norm, agg);
  }

  k_out<<<NN / 32, 256, 0, stream>>>(feats, agg, norm, cnt, efsum, Wedge, bedge,
                                     Wt, bmsg, bskip, out);
}

// Round 2
// 918.455 us; speedup vs baseline: 4.1269x; 4.1269x over previous
//
#include <hip/hip_runtime.h>

#define NN 100000
#define EM 1600000
#define EA 200000
#define ET (EM + EA)

// ws layout (4B units):
//   deg[NN] | cnt[NN](int) | cursor[NN](int) | norm[NN] | Wt[32768] | recSC[2*ET](int2) | recEF[4*ET](float4)
// total = 4*NN + 32768 + 6*ET = 11,232,768 floats = 44.9 MB
#define OFF_DEG  0
#define OFF_CNT  (NN)
#define OFF_CUR  (2*NN)
#define OFF_NORM (3*NN)
#define OFF_WT   (4*NN)
#define OFF_RSC  (4*NN + 32768)
#define OFF_REF  (4*NN + 32768 + 2*ET)

__global__ __launch_bounds__(256) void k_count(
    const int* __restrict__ srcE, const int* __restrict__ dstE,
    const int* __restrict__ dstA,
    float* __restrict__ deg, int* __restrict__ cnt) {
  int e = blockIdx.x * 256 + threadIdx.x;
  if (e < EM) {
    unsafeAtomicAdd(&deg[srcE[e]], 1.0f);
    atomicAdd(&cnt[dstE[e]], 1);
  } else if (e < ET) {
    atomicAdd(&cnt[dstA[e - EM]], 1);
  }
}

__global__ __launch_bounds__(256) void k_norm_wt(
    const float* __restrict__ deg, float* __restrict__ norm,
    const float* __restrict__ Wmsg, const float* __restrict__ Wskip,
    float* __restrict__ Wt) {
  int i = blockIdx.x * 256 + threadIdx.x;
  if (i < NN) {
    float dg = deg[i];
    norm[i] = dg > 0.0f ? rsqrtf(dg) : 0.0f;
  }
  if (i < 128 * 128) {
    int j = i >> 7, k = i & 127;
    Wt[k * 128 + j]         = Wmsg[j * 128 + k];   // Wt[k][j] = Wmsg[j][k]
    Wt[16384 + k * 128 + j] = Wskip[j * 128 + k];
  }
}

// single-workgroup exclusive scan: cursor[i] = sum_{j<i} cnt[j]
__global__ __launch_bounds__(1024) void k_scan(const int* __restrict__ cnt,
                                               int* __restrict__ cursor) {
  __shared__ int wsum[16];
  __shared__ int carry_s;
  int tid = threadIdx.x, lane = tid & 63, wid = tid >> 6;
  if (tid == 0) carry_s = 0;
  __syncthreads();
  for (int base = 0; base < NN; base += 1024) {
    int i = base + tid;
    int v = (i < NN) ? cnt[i] : 0;
    int x = v;
#pragma unroll
    for (int s = 1; s < 64; s <<= 1) {
      int y = __shfl_up(x, s, 64);
      if (lane >= s) x += y;
    }
    if (lane == 63) wsum[wid] = x;
    __syncthreads();
    if (tid == 0) {
      int a = carry_s;
#pragma unroll
      for (int w = 0; w < 16; ++w) { int t = wsum[w]; wsum[w] = a; a += t; }
      carry_s = a;
    }
    __syncthreads();
    int excl = wsum[wid] + x - v;
    if (i < NN) cursor[i] = excl;
    __syncthreads();  // wsum/carry_s reused next iter
  }
}

// bucket edges by dst: recSC[slot]=(src, att*norm[src]), recEF[slot]=ef (0 for acc)
__global__ __launch_bounds__(256) void k_fill(
    const int* __restrict__ srcE, const int* __restrict__ dstE,
    const int* __restrict__ srcA, const int* __restrict__ dstA,
    const float* __restrict__ ef, const float* __restrict__ Watt,
    const float* __restrict__ batt, const float* __restrict__ norm,
    int* __restrict__ cursor, int2* __restrict__ recSC, float4* __restrict__ recEF) {
  int e = blockIdx.x * 256 + threadIdx.x;
  if (e >= ET) return;
  int s, d;
  float att;
  float4 f;
  if (e < EM) {
    s = srcE[e]; d = dstE[e];
    f = ((const float4*)ef)[e];
    float z = f.x * Watt[0] + f.y * Watt[1] + f.z * Watt[2] + f.w * Watt[3] + batt[0];
    att = 1.0f / (1.0f + __expf(-z));
  } else {
    int ea = e - EM;
    s = srcA[ea]; d = dstA[ea];
    f = make_float4(0.f, 0.f, 0.f, 0.f);
    att = 1.0f / (1.0f + __expf(-batt[0]));
  }
  float c = att * norm[s];
  int slot = atomicAdd(&cursor[d], 1);
  recSC[slot] = make_int2(s, __float_as_int(c));
  recEF[slot] = f;
}

// Fused pull + output GEMM. Block: 256 threads = 4 waves, 32 nodes.
// Phase A: wave w pulls nodes [w*8, w*8+8): acc = sum c*h[src] (float2/lane),
//          epilogue folds W_edge@efsum + len*(b_edge + nm*feats[n]) then *nm,
//          stages x[k][nn] (k<128: rst, k>=128: feats) into LDS.
// Phase B: 32x128 GEMM vs Wt[256][128], 4x4 per thread (same as R1 k_out).
__global__ __launch_bounds__(256) void k_pull_out(
    const float* __restrict__ feats, const int* __restrict__ cnt,
    const int* __restrict__ cursor, const float* __restrict__ norm,
    const int2* __restrict__ recSC, const float4* __restrict__ recEF,
    const float* __restrict__ Wedge, const float* __restrict__ bedge,
    const float* __restrict__ Wt, const float* __restrict__ bmsg,
    const float* __restrict__ bskip, float* __restrict__ out) {
  __shared__ float x[256 * 33];
  int n0 = blockIdx.x * 32;
  int tid = threadIdx.x;
  int lane = tid & 63, wid = tid >> 6;

  for (int nn = wid * 8; nn < wid * 8 + 8; ++nn) {
    int n = n0 + nn;
    int end = cursor[n];
    int beg = end - cnt[n];
    float2 acc = make_float2(0.f, 0.f);
    float4 efa = make_float4(0.f, 0.f, 0.f, 0.f);
    for (int e = beg; e < end; ++e) {
      int2 sc = recSC[e];
      float4 fe = recEF[e];
      int s = sc.x;
      float c = __int_as_float(sc.y);
      float2 h = ((const float2*)feats)[s * 64 + lane];
      acc.x += c * h.x;
      acc.y += c * h.y;
      efa.x += fe.x; efa.y += fe.y; efa.z += fe.z; efa.w += fe.w;
    }
    float len = (float)(end - beg);
    float nm = norm[n];
    float2 f = ((const float2*)feats)[n * 64 + lane];
    float4 wa = ((const float4*)Wedge)[2 * lane + 0];   // W_edge row 2*lane
    float4 wb = ((const float4*)Wedge)[2 * lane + 1];
    float2 be = ((const float2*)bedge)[lane];
    float tx = wa.x * efa.x + wa.y * efa.y + wa.z * efa.z + wa.w * efa.w;
    float ty = wb.x * efa.x + wb.y * efa.y + wb.z * efa.z + wb.w * efa.w;
    float rx = (acc.x + tx + len * (be.x + nm * f.x)) * nm;
    float ry = (acc.y + ty + len * (be.y + nm * f.y)) * nm;
    x[(2 * lane + 0) * 33 + nn] = rx;
    x[(2 * lane + 1) * 33 + nn] = ry;
    x[(128 + 2 * lane + 0) * 33 + nn] = f.x;
    x[(128 + 2 * lane + 1) * 33 + nn] = f.y;
  }
  __syncthreads();

  int jg = tid & 31;
  int ng = tid >> 5;
  float acc[4][4] = {{0.f}};
#pragma unroll 4
  for (int k = 0; k < 256; ++k) {
    float4 w = ((const float4*)(Wt + k * 128))[jg];
    float x0 = x[k * 33 + 4 * ng + 0];
    float x1 = x[k * 33 + 4 * ng + 1];
    float x2 = x[k * 33 + 4 * ng + 2];
    float x3 = x[k * 33 + 4 * ng + 3];
    acc[0][0] += x0 * w.x; acc[0][1] += x0 * w.y; acc[0][2] += x0 * w.z; acc[0][3] += x0 * w.w;
    acc[1][0] += x1 * w.x; acc[1][1] += x1 * w.y; acc[1][2] += x1 * w.z; acc[1][3] += x1 * w.w;
    acc[2][0] += x2 * w.x; acc[2][1] += x2 * w.y; acc[2][2] += x2 * w.z; acc[2][3] += x2 * w.w;
    acc[3][0] += x3 * w.x; acc[3][1] += x3 * w.y; acc[3][2] += x3 * w.z; acc[3][3] += x3 * w.w;
  }
  float4 bm = ((const float4*)bmsg)[jg];
  float4 bs = ((const float4*)bskip)[jg];
  float b0 = bm.x + bs.x, b1 = bm.y + bs.y, b2 = bm.z + bs.z, b3 = bm.w + bs.w;
#pragma unroll
  for (int i = 0; i < 4; ++i) {
    int n = n0 + 4 * ng + i;
    ((float4*)out)[n * 32 + jg] = make_float4(acc[i][0] + b0, acc[i][1] + b1,
                                              acc[i][2] + b2, acc[i][3] + b3);
  }
}

extern "C" void kernel_launch(void* const* d_in, const int* in_sizes, int n_in,
                              void* d_out, int out_size, void* d_ws, size_t ws_size,
                              hipStream_t stream) {
  const float* feats  = (const float*)d_in[0];
  const float* ef     = (const float*)d_in[1];
  const int*   srcE   = (const int*)d_in[2];
  const int*   dstE   = (const int*)d_in[3];
  const int*   srcA   = (const int*)d_in[4];
  const int*   dstA   = (const int*)d_in[5];
  const float* Wskip  = (const float*)d_in[6];
  const float* bskip  = (const float*)d_in[7];
  const float* Wmsg   = (const float*)d_in[8];
  const float* bmsg   = (const float*)d_in[9];
  const float* Wedge  = (const float*)d_in[10];
  const float* bedge  = (const float*)d_in[11];
  const float* Watt   = (const float*)d_in[12];
  const float* batt   = (const float*)d_in[13];
  float* out = (float*)d_out;
  float* ws  = (float*)d_ws;

  float* deg    = ws + OFF_DEG;
  int*   cnt    = (int*)(ws + OFF_CNT);
  int*   cursor = (int*)(ws + OFF_CUR);
  float* norm   = ws + OFF_NORM;
  float* Wt     = ws + OFF_WT;
  int2*  recSC  = (int2*)(ws + OFF_RSC);
  float4* recEF = (float4*)(ws + OFF_REF);

  hipMemsetAsync(ws, 0, (size_t)(2 * NN) * sizeof(float), stream);  // deg + cnt

  k_count<<<(ET + 255) / 256, 256, 0, stream>>>(srcE, dstE, dstA, deg, cnt);
  k_norm_wt<<<(NN + 255) / 256, 256, 0, stream>>>(deg, norm, Wmsg, Wskip, Wt);
  k_scan<<<1, 1024, 0, stream>>>(cnt, cursor);
  k_fill<<<(ET + 255) / 256, 256, 0, stream>>>(srcE, dstE, srcA, dstA, ef, Watt,
                                               batt, norm, cursor, recSC, recEF);
  k_pull_out<<<NN / 32, 256, 0, stream>>>(feats, cnt, cursor, norm, recSC, recEF,
                                          Wedge, bedge, Wt, bmsg, bskip, out);
}

// Round 3
// 635.475 us; speedup vs baseline: 5.9646x; 1.4453x over previous
//
#include <hip/hip_runtime.h>
#include <hip/hip_bf16.h>

#define NN 100000
#define EM 1600000
#define EA 200000
#define ET (EM + EA)
#define SB 98   // scan blocks of 1024: 98*1024 >= NN

// ws layout (4B units):
//  norm[NN] (deg in-place) | cnt[NN] int | cursor[NN] int | bsum[128] int |
//  Wt[32768] | recSC[ET] uint | recEF[2*ET] uint2 | featsb[64*NN] uint
// total = 3*NN + 128 + 32768 + 3*ET + 64*NN = 12,132,896 floats = 48.5 MB
#define OFF_NORM 0
#define OFF_CNT  (NN)
#define OFF_CUR  (2*NN)
#define OFF_BSUM (3*NN)
#define OFF_WT   (3*NN + 128)
#define OFF_RSC  (3*NN + 128 + 32768)
#define OFF_REF  (OFF_RSC + ET)
#define OFF_FB   (OFF_REF + 2*ET)

#define UNP_LO(u) __uint_as_float((u) << 16)
#define UNP_HI(u) __uint_as_float((u) & 0xFFFF0000u)

__global__ __launch_bounds__(256) void k_count(
    const int* __restrict__ srcE, const int* __restrict__ dstE,
    const int* __restrict__ dstA,
    float* __restrict__ deg, int* __restrict__ cnt) {
  int e = blockIdx.x * 256 + threadIdx.x;
  if (e < EM) {
    unsafeAtomicAdd(&deg[srcE[e]], 1.0f);
    atomicAdd(&cnt[dstE[e]], 1);
  } else if (e < ET) {
    atomicAdd(&cnt[dstA[e - EM]], 1);
  }
}

__global__ __launch_bounds__(256) void k_norm_wt(
    float* __restrict__ norm,   // holds deg on entry; rsqrt in place
    const float* __restrict__ Wmsg, const float* __restrict__ Wskip,
    float* __restrict__ Wt) {
  int i = blockIdx.x * 256 + threadIdx.x;
  if (i < NN) {
    float dg = norm[i];
    norm[i] = dg > 0.0f ? rsqrtf(dg) : 0.0f;
  }
  if (i < 128 * 128) {
    int j = i >> 7, k = i & 127;
    Wt[k * 128 + j]         = Wmsg[j * 128 + k];
    Wt[16384 + k * 128 + j] = Wskip[j * 128 + k];
  }
}

// pack feats rows to bf16 pairs: featsb[n*64 + p] = (bf16(col 2p+1)<<16)|bf16(col 2p)
__global__ __launch_bounds__(256) void k_convert(
    const float* __restrict__ feats, unsigned* __restrict__ featsb) {
  int i = blockIdx.x * 256 + threadIdx.x;
  if (i < NN * 64) {
    float2 f = ((const float2*)feats)[i];
    union { __hip_bfloat162 b; unsigned u; } cv;
    cv.b = __float22bfloat162_rn(f);
    featsb[i] = cv.u;
  }
}

__global__ __launch_bounds__(1024) void k_scan1(const int* __restrict__ cnt,
                                                int* __restrict__ bsum) {
  __shared__ int ws16[16];
  int tid = threadIdx.x, lane = tid & 63, wid = tid >> 6;
  int i = blockIdx.x * 1024 + tid;
  int v = (i < NN) ? cnt[i] : 0;
#pragma unroll
  for (int s = 1; s < 64; s <<= 1) v += __shfl_xor(v, s, 64);
  if (lane == 0) ws16[wid] = v;
  __syncthreads();
  if (tid == 0) {
    int a = 0;
#pragma unroll
    for (int w = 0; w < 16; ++w) a += ws16[w];
    bsum[blockIdx.x] = a;
  }
}

__global__ __launch_bounds__(64) void k_scan2(int* __restrict__ bsum) {
  int lane = threadIdx.x;
  int v0 = (lane < SB) ? bsum[lane] : 0;
  int v1 = (64 + lane < SB) ? bsum[64 + lane] : 0;
  int x0 = v0, x1 = v1;
#pragma unroll
  for (int s = 1; s < 64; s <<= 1) {
    int y = __shfl_up(x0, s, 64); if (lane >= s) x0 += y;
  }
#pragma unroll
  for (int s = 1; s < 64; s <<= 1) {
    int y = __shfl_up(x1, s, 64); if (lane >= s) x1 += y;
  }
  int t0 = __shfl(x0, 63, 64);
  if (lane < SB) bsum[lane] = x0 - v0;
  if (64 + lane < SB) bsum[64 + lane] = t0 + x1 - v1;
}

__global__ __launch_bounds__(1024) void k_scan3(const int* __restrict__ cnt,
                                                const int* __restrict__ bsum,
                                                int* __restrict__ cursor) {
  __shared__ int ws16[16];
  int tid = threadIdx.x, lane = tid & 63, wid = tid >> 6;
  int i = blockIdx.x * 1024 + tid;
  int v = (i < NN) ? cnt[i] : 0;
  int x = v;
#pragma unroll
  for (int s = 1; s < 64; s <<= 1) {
    int y = __shfl_up(x, s, 64); if (lane >= s) x += y;
  }
  if (lane == 63) ws16[wid] = x;
  __syncthreads();
  if (tid == 0) {
    int a = bsum[blockIdx.x];
#pragma unroll
    for (int w = 0; w < 16; ++w) { int t = ws16[w]; ws16[w] = a; a += t; }
  }
  __syncthreads();
  if (i < NN) cursor[i] = ws16[wid] + x - v;
}

// bucket by dst: recSC[slot] = (src<<15)|q15(att*norm[src]); recEF[slot] = bf16x4(ef)
__global__ __launch_bounds__(256) void k_fill(
    const int* __restrict__ srcE, const int* __restrict__ dstE,
    const int* __restrict__ srcA, const int* __restrict__ dstA,
    const float* __restrict__ ef, const float* __restrict__ Watt,
    const float* __restrict__ batt, const float* __restrict__ norm,
    int* __restrict__ cursor, unsigned* __restrict__ recSC,
    uint2* __restrict__ recEF) {
  int e = blockIdx.x * 256 + threadIdx.x;
  if (e >= ET) return;
  int s, d;
  float att;
  float4 f;
  if (e < EM) {
    s = srcE[e]; d = dstE[e];
    f = ((const float4*)ef)[e];
    float z = f.x * Watt[0] + f.y * Watt[1] + f.z * Watt[2] + f.w * Watt[3] + batt[0];
    att = 1.0f / (1.0f + __expf(-z));
  } else {
    int ea = e - EM;
    s = srcA[ea]; d = dstA[ea];
    f = make_float4(0.f, 0.f, 0.f, 0.f);
    att = 1.0f / (1.0f + __expf(-batt[0]));
  }
  float c = att * norm[s];
  unsigned q = (unsigned)(c * 32767.0f + 0.5f);
  if (q > 32767u) q = 32767u;
  int slot = atomicAdd(&cursor[d], 1);
  recSC[slot] = ((unsigned)s << 15) | q;
  union { __hip_bfloat162 b; unsigned u; } c01, c23;
  c01.b = __float22bfloat162_rn(make_float2(f.x, f.y));
  c23.b = __float22bfloat162_rn(make_float2(f.z, f.w));
  recEF[slot] = make_uint2(c01.u, c23.u);
}

// Fused pull + GEMM. 256 thr = 4 waves, 32 nodes/block; wave handles 8 nodes.
// Pull loop unrolled x4: uniform record loads, 4 independent bf16 gathers in flight.
__global__ __launch_bounds__(256) void k_pull_out(
    const float* __restrict__ feats, const unsigned* __restrict__ featsb,
    const int* __restrict__ cnt, const int* __restrict__ cursor,
    const float* __restrict__ norm, const unsigned* __restrict__ recSC,
    const uint2* __restrict__ recEF,
    const float* __restrict__ Wedge, const float* __restrict__ bedge,
    const float* __restrict__ Wt, const float* __restrict__ bmsg,
    const float* __restrict__ bskip, float* __restrict__ out) {
  __shared__ float x[256 * 33];
  int n0 = blockIdx.x * 32;
  int tid = threadIdx.x;
  int lane = tid & 63, wid = tid >> 6;

  for (int nn = wid * 8; nn < wid * 8 + 8; ++nn) {
    int n = n0 + nn;
    int end = __builtin_amdgcn_readfirstlane(cursor[n]);   // post-fill = bucket end
    int beg = end - __builtin_amdgcn_readfirstlane(cnt[n]);
    float2 acc = make_float2(0.f, 0.f);
    float4 efa = make_float4(0.f, 0.f, 0.f, 0.f);
    int e = beg;
    for (; e + 4 <= end; e += 4) {
      unsigned r0 = recSC[e], r1 = recSC[e + 1], r2 = recSC[e + 2], r3 = recSC[e + 3];
      uint2 g0 = recEF[e], g1 = recEF[e + 1], g2 = recEF[e + 2], g3 = recEF[e + 3];
      unsigned u0 = featsb[(r0 >> 15) * 64 + lane];
      unsigned u1 = featsb[(r1 >> 15) * 64 + lane];
      unsigned u2 = featsb[(r2 >> 15) * 64 + lane];
      unsigned u3 = featsb[(r3 >> 15) * 64 + lane];
      float c0 = (float)(r0 & 32767u) * (1.0f / 32767.0f);
      float c1 = (float)(r1 & 32767u) * (1.0f / 32767.0f);
      float c2 = (float)(r2 & 32767u) * (1.0f / 32767.0f);
      float c3 = (float)(r3 & 32767u) * (1.0f / 32767.0f);
      acc.x += c0 * UNP_LO(u0) + c1 * UNP_LO(u1) + c2 * UNP_LO(u2) + c3 * UNP_LO(u3);
      acc.y += c0 * UNP_HI(u0) + c1 * UNP_HI(u1) + c2 * UNP_HI(u2) + c3 * UNP_HI(u3);
      efa.x += UNP_LO(g0.x) + UNP_LO(g1.x) + UNP_LO(g2.x) + UNP_LO(g3.x);
      efa.y += UNP_HI(g0.x) + UNP_HI(g1.x) + UNP_HI(g2.x) + UNP_HI(g3.x);
      efa.z += UNP_LO(g0.y) + UNP_LO(g1.y) + UNP_LO(g2.y) + UNP_LO(g3.y);
      efa.w += UNP_HI(g0.y) + UNP_HI(g1.y) + UNP_HI(g2.y) + UNP_HI(g3.y);
    }
    for (; e < end; ++e) {
      unsigned r = recSC[e];
      uint2 g = recEF[e];
      unsigned u = featsb[(r >> 15) * 64 + lane];
      float c = (float)(r & 32767u) * (1.0f / 32767.0f);
      acc.x += c * UNP_LO(u);
      acc.y += c * UNP_HI(u);
      efa.x += UNP_LO(g.x); efa.y += UNP_HI(g.x);
      efa.z += UNP_LO(g.y); efa.w += UNP_HI(g.y);
    }
    float len = (float)(end - beg);
    float nm = norm[n];
    float2 f = ((const float2*)feats)[n * 64 + lane];
    float4 wa = ((const float4*)Wedge)[2 * lane + 0];
    float4 wb = ((const float4*)Wedge)[2 * lane + 1];
    float2 be = ((const float2*)bedge)[lane];
    float tx = wa.x * efa.x + wa.y * efa.y + wa.z * efa.z + wa.w * efa.w;
    float ty = wb.x * efa.x + wb.y * efa.y + wb.z * efa.z + wb.w * efa.w;
    float rx = (acc.x + tx + len * (be.x + nm * f.x)) * nm;
    float ry = (acc.y + ty + len * (be.y + nm * f.y)) * nm;
    x[(2 * lane + 0) * 33 + nn] = rx;
    x[(2 * lane + 1) * 33 + nn] = ry;
    x[(128 + 2 * lane + 0) * 33 + nn] = f.x;
    x[(128 + 2 * lane + 1) * 33 + nn] = f.y;
  }
  __syncthreads();

  int jg = tid & 31;
  int ng = tid >> 5;
  float acc[4][4] = {{0.f}};
#pragma unroll 4
  for (int k = 0; k < 256; ++k) {
    float4 w = ((const float4*)(Wt + k * 128))[jg];
    float x0 = x[k * 33 + 4 * ng + 0];
    float x1 = x[k * 33 + 4 * ng + 1];
    float x2 = x[k * 33 + 4 * ng + 2];
    float x3 = x[k * 33 + 4 * ng + 3];
    acc[0][0] += x0 * w.x; acc[0][1] += x0 * w.y; acc[0][2] += x0 * w.z; acc[0][3] += x0 * w.w;
    acc[1][0] += x1 * w.x; acc[1][1] += x1 * w.y; acc[1][2] += x1 * w.z; acc[1][3] += x1 * w.w;
    acc[2][0] += x2 * w.x; acc[2][1] += x2 * w.y; acc[2][2] += x2 * w.z; acc[2][3] += x2 * w.w;
    acc[3][0] += x3 * w.x; acc[3][1] += x3 * w.y; acc[3][2] += x3 * w.z; acc[3][3] += x3 * w.w;
  }
  float4 bm = ((const float4*)bmsg)[jg];
  float4 bs = ((const float4*)bskip)[jg];
  float b0 = bm.x + bs.x, b1 = bm.y + bs.y, b2 = bm.z + bs.z, b3 = bm.w + bs.w;
#pragma unroll
  for (int i = 0; i < 4; ++i) {
    int n = n0 + 4 * ng + i;
    ((float4*)out)[n * 32 + jg] = make_float4(acc[i][0] + b0, acc[i][1] + b1,
                                              acc[i][2] + b2, acc[i][3] + b3);
  }
}

extern "C" void kernel_launch(void* const* d_in, const int* in_sizes, int n_in,
                              void* d_out, int out_size, void* d_ws, size_t ws_size,
                              hipStream_t stream) {
  const float* feats  = (const float*)d_in[0];
  const float* ef     = (const float*)d_in[1];
  const int*   srcE   = (const int*)d_in[2];
  const int*   dstE   = (const int*)d_in[3];
  const int*   srcA   = (const int*)d_in[4];
  const int*   dstA   = (const int*)d_in[5];
  const float* Wskip  = (const float*)d_in[6];
  const float* bskip  = (const float*)d_in[7];
  const float* Wmsg   = (const float*)d_in[8];
  const float* bmsg   = (const float*)d_in[9];
  const float* Wedge  = (const float*)d_in[10];
  const float* bedge  = (const float*)d_in[11];
  const float* Watt   = (const float*)d_in[12];
  const float* batt   = (const float*)d_in[13];
  float* out = (float*)d_out;
  float* ws  = (float*)d_ws;

  float*    norm   = ws + OFF_NORM;
  int*      cnt    = (int*)(ws + OFF_CNT);
  int*      cursor = (int*)(ws + OFF_CUR);
  int*      bsum   = (int*)(ws + OFF_BSUM);
  float*    Wt     = ws + OFF_WT;
  unsigned* recSC  = (unsigned*)(ws + OFF_RSC);
  uint2*    recEF  = (uint2*)(ws + OFF_REF);
  unsigned* featsb = (unsigned*)(ws + OFF_FB);

  hipMemsetAsync(ws, 0, (size_t)(2 * NN) * sizeof(float), stream);  // deg + cnt

  k_count<<<(ET + 255) / 256, 256, 0, stream>>>(srcE, dstE, dstA, norm, cnt);
  k_norm_wt<<<(NN + 255) / 256, 256, 0, stream>>>(norm, Wmsg, Wskip, Wt);
  k_convert<<<(NN * 64 + 255) / 256, 256, 0, stream>>>(feats, featsb);
  k_scan1<<<SB, 1024, 0, stream>>>(cnt, bsum);
  k_scan2<<<1, 64, 0, stream>>>(bsum);
  k_scan3<<<SB, 1024, 0, stream>>>(cnt, bsum, cursor);
  k_fill<<<(ET + 255) / 256, 256, 0, stream>>>(srcE, dstE, srcA, dstA, ef, Watt,
                                               batt, norm, cursor, recSC, recEF);
  k_pull_out<<<NN / 32, 256, 0, stream>>>(feats, featsb, cnt, cursor, norm,
                                          recSC, recEF, Wedge, bedge, Wt,
                                          bmsg, bskip, out);
}

// Round 4
// 619.513 us; speedup vs baseline: 6.1183x; 1.0258x over previous
//
#include <hip/hip_runtime.h>
#include <hip/hip_bf16.h>

#define NN 100000
#define EM 1600000
#define EA 200000
#define ET (EM + EA)
#define SB 98   // scan blocks of 1024: 98*1024 >= NN

// ws layout (4B units):
//  norm[NN] (deg in-place) | cnt[NN] int | cursor[NN] int | bsum[128] int |
//  Wt[32768] | recSC[ET] uint | recEF[2*ET] uint2 | featsb[64*NN] uint | rank16[ET] ushort
// total = 3*NN + 128 + 32768 + 3*ET + 64*NN + ET/2 = 13,032,896 dwords = 52.1 MB
#define OFF_NORM 0
#define OFF_CNT  (NN)
#define OFF_CUR  (2*NN)
#define OFF_BSUM (3*NN)
#define OFF_WT   (3*NN + 128)
#define OFF_RSC  (3*NN + 128 + 32768)
#define OFF_REF  (OFF_RSC + ET)
#define OFF_FB   (OFF_REF + 2*ET)
#define OFF_RANK (OFF_FB + 64*NN)

#define UNP_LO(u) __uint_as_float((u) << 16)
#define UNP_HI(u) __uint_as_float((u) & 0xFFFF0000u)

// count degrees; save each edge's arrival rank within its dst bucket (free: we
// already pay this atomic, just keep the return value)
__global__ __launch_bounds__(256) void k_count(
    const int* __restrict__ srcE, const int* __restrict__ dstE,
    const int* __restrict__ dstA,
    float* __restrict__ deg, int* __restrict__ cnt,
    unsigned short* __restrict__ rank16) {
  int e = blockIdx.x * 256 + threadIdx.x;
  if (e < EM) {
    unsafeAtomicAdd(&deg[srcE[e]], 1.0f);
    int r = atomicAdd(&cnt[dstE[e]], 1);
    rank16[e] = (unsigned short)r;
  } else if (e < ET) {
    int r = atomicAdd(&cnt[dstA[e - EM]], 1);
    rank16[e] = (unsigned short)r;
  }
}

__global__ __launch_bounds__(256) void k_norm_wt(
    float* __restrict__ norm,   // holds deg on entry; rsqrt in place
    const float* __restrict__ Wmsg, const float* __restrict__ Wskip,
    float* __restrict__ Wt) {
  int i = blockIdx.x * 256 + threadIdx.x;
  if (i < NN) {
    float dg = norm[i];
    norm[i] = dg > 0.0f ? rsqrtf(dg) : 0.0f;
  }
  if (i < 128 * 128) {
    int j = i >> 7, k = i & 127;
    Wt[k * 128 + j]         = Wmsg[j * 128 + k];
    Wt[16384 + k * 128 + j] = Wskip[j * 128 + k];
  }
}

__global__ __launch_bounds__(256) void k_convert(
    const float* __restrict__ feats, unsigned* __restrict__ featsb) {
  int i = blockIdx.x * 256 + threadIdx.x;
  if (i < NN * 64) {
    float2 f = ((const float2*)feats)[i];
    union { __hip_bfloat162 b; unsigned u; } cv;
    cv.b = __float22bfloat162_rn(f);
    featsb[i] = cv.u;
  }
}

__global__ __launch_bounds__(1024) void k_scan1(const int* __restrict__ cnt,
                                                int* __restrict__ bsum) {
  __shared__ int ws16[16];
  int tid = threadIdx.x, lane = tid & 63, wid = tid >> 6;
  int i = blockIdx.x * 1024 + tid;
  int v = (i < NN) ? cnt[i] : 0;
#pragma unroll
  for (int s = 1; s < 64; s <<= 1) v += __shfl_xor(v, s, 64);
  if (lane == 0) ws16[wid] = v;
  __syncthreads();
  if (tid == 0) {
    int a = 0;
#pragma unroll
    for (int w = 0; w < 16; ++w) a += ws16[w];
    bsum[blockIdx.x] = a;
  }
}

__global__ __launch_bounds__(64) void k_scan2(int* __restrict__ bsum) {
  int lane = threadIdx.x;
  int v0 = (lane < SB) ? bsum[lane] : 0;
  int v1 = (64 + lane < SB) ? bsum[64 + lane] : 0;
  int x0 = v0, x1 = v1;
#pragma unroll
  for (int s = 1; s < 64; s <<= 1) {
    int y = __shfl_up(x0, s, 64); if (lane >= s) x0 += y;
  }
#pragma unroll
  for (int s = 1; s < 64; s <<= 1) {
    int y = __shfl_up(x1, s, 64); if (lane >= s) x1 += y;
  }
  int t0 = __shfl(x0, 63, 64);
  if (lane < SB) bsum[lane] = x0 - v0;
  if (64 + lane < SB) bsum[64 + lane] = t0 + x1 - v1;
}

__global__ __launch_bounds__(1024) void k_scan3(const int* __restrict__ cnt,
                                                const int* __restrict__ bsum,
                                                int* __restrict__ cursor) {
  __shared__ int ws16[16];
  int tid = threadIdx.x, lane = tid & 63, wid = tid >> 6;
  int i = blockIdx.x * 1024 + tid;
  int v = (i < NN) ? cnt[i] : 0;
  int x = v;
#pragma unroll
  for (int s = 1; s < 64; s <<= 1) {
    int y = __shfl_up(x, s, 64); if (lane >= s) x += y;
  }
  if (lane == 63) ws16[wid] = x;
  __syncthreads();
  if (tid == 0) {
    int a = bsum[blockIdx.x];
#pragma unroll
    for (int w = 0; w < 16; ++w) { int t = ws16[w]; ws16[w] = a; a += t; }
  }
  __syncthreads();
  if (i < NN) cursor[i] = ws16[wid] + x - v;   // exclusive start of bucket
}

// bucket by dst, atomic-free: slot = cursor[d] + rank16[e]
__global__ __launch_bounds__(256) void k_fill(
    const int* __restrict__ srcE, const int* __restrict__ dstE,
    const int* __restrict__ srcA, const int* __restrict__ dstA,
    const float* __restrict__ ef, const float* __restrict__ Watt,
    const float* __restrict__ batt, const float* __restrict__ norm,
    const int* __restrict__ cursor, const unsigned short* __restrict__ rank16,
    unsigned* __restrict__ recSC, uint2* __restrict__ recEF) {
  int e = blockIdx.x * 256 + threadIdx.x;
  if (e >= ET) return;
  int s, d;
  float att;
  float4 f;
  if (e < EM) {
    s = srcE[e]; d = dstE[e];
    f = ((const float4*)ef)[e];
    float z = f.x * Watt[0] + f.y * Watt[1] + f.z * Watt[2] + f.w * Watt[3] + batt[0];
    att = 1.0f / (1.0f + __expf(-z));
  } else {
    int ea = e - EM;
    s = srcA[ea]; d = dstA[ea];
    f = make_float4(0.f, 0.f, 0.f, 0.f);
    att = 1.0f / (1.0f + __expf(-batt[0]));
  }
  float c = att * norm[s];
  unsigned q = (unsigned)(c * 32767.0f + 0.5f);
  if (q > 32767u) q = 32767u;
  int slot = cursor[d] + (int)rank16[e];
  recSC[slot] = ((unsigned)s << 15) | q;
  union { __hip_bfloat162 b; unsigned u; } c01, c23;
  c01.b = __float22bfloat162_rn(make_float2(f.x, f.y));
  c23.b = __float22bfloat162_rn(make_float2(f.z, f.w));
  recEF[slot] = make_uint2(c01.u, c23.u);
}

// Fused pull + GEMM. 256 thr = 4 waves, 32 nodes/block; wave handles 8 nodes.
// Main loop: unroll x8, pure gather+FMA (ef handled in a separate lane-parallel
// pass so 64 lanes don't redundantly accumulate the wave-uniform ef sum).
__global__ __launch_bounds__(256) void k_pull_out(
    const float* __restrict__ feats, const unsigned* __restrict__ featsb,
    const int* __restrict__ cnt, const int* __restrict__ cursor,
    const float* __restrict__ norm, const unsigned* __restrict__ recSC,
    const uint2* __restrict__ recEF,
    const float* __restrict__ Wedge, const float* __restrict__ bedge,
    const float* __restrict__ Wt, const float* __restrict__ bmsg,
    const float* __restrict__ bskip, float* __restrict__ out) {
  __shared__ float x[256 * 33];
  int n0 = blockIdx.x * 32;
  int tid = threadIdx.x;
  int lane = tid & 63, wid = tid >> 6;

  for (int nn = wid * 8; nn < wid * 8 + 8; ++nn) {
    int n = n0 + nn;
    int beg = __builtin_amdgcn_readfirstlane(cursor[n]);
    int len = __builtin_amdgcn_readfirstlane(cnt[n]);
    int end = beg + len;
    float2 acc = make_float2(0.f, 0.f);
    int e = beg;
    for (; e + 8 <= end; e += 8) {
      unsigned r0 = recSC[e+0], r1 = recSC[e+1], r2 = recSC[e+2], r3 = recSC[e+3];
      unsigned r4 = recSC[e+4], r5 = recSC[e+5], r6 = recSC[e+6], r7 = recSC[e+7];
      unsigned u0 = featsb[(r0 >> 15) * 64 + lane];
      unsigned u1 = featsb[(r1 >> 15) * 64 + lane];
      unsigned u2 = featsb[(r2 >> 15) * 64 + lane];
      unsigned u3 = featsb[(r3 >> 15) * 64 + lane];
      unsigned u4 = featsb[(r4 >> 15) * 64 + lane];
      unsigned u5 = featsb[(r5 >> 15) * 64 + lane];
      unsigned u6 = featsb[(r6 >> 15) * 64 + lane];
      unsigned u7 = featsb[(r7 >> 15) * 64 + lane];
      float c0 = (float)(r0 & 32767u) * (1.0f / 32767.0f);
      float c1 = (float)(r1 & 32767u) * (1.0f / 32767.0f);
      float c2 = (float)(r2 & 32767u) * (1.0f / 32767.0f);
      float c3 = (float)(r3 & 32767u) * (1.0f / 32767.0f);
      float c4 = (float)(r4 & 32767u) * (1.0f / 32767.0f);
      float c5 = (float)(r5 & 32767u) * (1.0f / 32767.0f);
      float c6 = (float)(r6 & 32767u) * (1.0f / 32767.0f);
      float c7 = (float)(r7 & 32767u) * (1.0f / 32767.0f);
      acc.x += c0 * UNP_LO(u0) + c1 * UNP_LO(u1) + c2 * UNP_LO(u2) + c3 * UNP_LO(u3)
             + c4 * UNP_LO(u4) + c5 * UNP_LO(u5) + c6 * UNP_LO(u6) + c7 * UNP_LO(u7);
      acc.y += c0 * UNP_HI(u0) + c1 * UNP_HI(u1) + c2 * UNP_HI(u2) + c3 * UNP_HI(u3)
             + c4 * UNP_HI(u4) + c5 * UNP_HI(u5) + c6 * UNP_HI(u6) + c7 * UNP_HI(u7);
    }
    for (; e < end; ++e) {
      unsigned r = recSC[e];
      unsigned u = featsb[(r >> 15) * 64 + lane];
      float c = (float)(r & 32767u) * (1.0f / 32767.0f);
      acc.x += c * UNP_LO(u);
      acc.y += c * UNP_HI(u);
    }
    // lane-parallel ef sum over the bucket, then butterfly all-reduce
    float4 efa = make_float4(0.f, 0.f, 0.f, 0.f);
    for (int b = beg + lane; b < end; b += 64) {
      uint2 g = recEF[b];
      efa.x += UNP_LO(g.x); efa.y += UNP_HI(g.x);
      efa.z += UNP_LO(g.y); efa.w += UNP_HI(g.y);
    }
#pragma unroll
    for (int s = 1; s < 64; s <<= 1) {
      efa.x += __shfl_xor(efa.x, s, 64);
      efa.y += __shfl_xor(efa.y, s, 64);
      efa.z += __shfl_xor(efa.z, s, 64);
      efa.w += __shfl_xor(efa.w, s, 64);
    }
    float flen = (float)len;
    float nm = norm[n];
    float2 f = ((const float2*)feats)[n * 64 + lane];
    float4 wa = ((const float4*)Wedge)[2 * lane + 0];
    float4 wb = ((const float4*)Wedge)[2 * lane + 1];
    float2 be = ((const float2*)bedge)[lane];
    float tx = wa.x * efa.x + wa.y * efa.y + wa.z * efa.z + wa.w * efa.w;
    float ty = wb.x * efa.x + wb.y * efa.y + wb.z * efa.z + wb.w * efa.w;
    float rx = (acc.x + tx + flen * (be.x + nm * f.x)) * nm;
    float ry = (acc.y + ty + flen * (be.y + nm * f.y)) * nm;
    x[(2 * lane + 0) * 33 + nn] = rx;
    x[(2 * lane + 1) * 33 + nn] = ry;
    x[(128 + 2 * lane + 0) * 33 + nn] = f.x;
    x[(128 + 2 * lane + 1) * 33 + nn] = f.y;
  }
  __syncthreads();

  int jg = tid & 31;
  int ng = tid >> 5;
  float acc[4][4] = {{0.f}};
#pragma unroll 4
  for (int k = 0; k < 256; ++k) {
    float4 w = ((const float4*)(Wt + k * 128))[jg];
    float x0 = x[k * 33 + 4 * ng + 0];
    float x1 = x[k * 33 + 4 * ng + 1];
    float x2 = x[k * 33 + 4 * ng + 2];
    float x3 = x[k * 33 + 4 * ng + 3];
    acc[0][0] += x0 * w.x; acc[0][1] += x0 * w.y; acc[0][2] += x0 * w.z; acc[0][3] += x0 * w.w;
    acc[1][0] += x1 * w.x; acc[1][1] += x1 * w.y; acc[1][2] += x1 * w.z; acc[1][3] += x1 * w.w;
    acc[2][0] += x2 * w.x; acc[2][1] += x2 * w.y; acc[2][2] += x2 * w.z; acc[2][3] += x2 * w.w;
    acc[3][0] += x3 * w.x; acc[3][1] += x3 * w.y; acc[3][2] += x3 * w.z; acc[3][3] += x3 * w.w;
  }
  float4 bm = ((const float4*)bmsg)[jg];
  float4 bs = ((const float4*)bskip)[jg];
  float b0 = bm.x + bs.x, b1 = bm.y + bs.y, b2 = bm.z + bs.z, b3 = bm.w + bs.w;
#pragma unroll
  for (int i = 0; i < 4; ++i) {
    int n = n0 + 4 * ng + i;
    ((float4*)out)[n * 32 + jg] = make_float4(acc[i][0] + b0, acc[i][1] + b1,
                                              acc[i][2] + b2, acc[i][3] + b3);
  }
}

extern "C" void kernel_launch(void* const* d_in, const int* in_sizes, int n_in,
                              void* d_out, int out_size, void* d_ws, size_t ws_size,
                              hipStream_t stream) {
  const float* feats  = (const float*)d_in[0];
  const float* ef     = (const float*)d_in[1];
  const int*   srcE   = (const int*)d_in[2];
  const int*   dstE   = (const int*)d_in[3];
  const int*   srcA   = (const int*)d_in[4];
  const int*   dstA   = (const int*)d_in[5];
  const float* Wskip  = (const float*)d_in[6];
  const float* bskip  = (const float*)d_in[7];
  const float* Wmsg   = (const float*)d_in[8];
  const float* bmsg   = (const float*)d_in[9];
  const float* Wedge  = (const float*)d_in[10];
  const float* bedge  = (const float*)d_in[11];
  const float* Watt   = (const float*)d_in[12];
  const float* batt   = (const float*)d_in[13];
  float* out = (float*)d_out;
  float* ws  = (float*)d_ws;

  float*          norm   = ws + OFF_NORM;
  int*            cnt    = (int*)(ws + OFF_CNT);
  int*            cursor = (int*)(ws + OFF_CUR);
  int*            bsum   = (int*)(ws + OFF_BSUM);
  float*          Wt     = ws + OFF_WT;
  unsigned*       recSC  = (unsigned*)(ws + OFF_RSC);
  uint2*          recEF  = (uint2*)(ws + OFF_REF);
  unsigned*       featsb = (unsigned*)(ws + OFF_FB);
  unsigned short* rank16 = (unsigned short*)(ws + OFF_RANK);

  hipMemsetAsync(ws, 0, (size_t)(2 * NN) * sizeof(float), stream);  // deg + cnt

  k_count<<<(ET + 255) / 256, 256, 0, stream>>>(srcE, dstE, dstA, norm, cnt, rank16);
  k_norm_wt<<<(NN + 255) / 256, 256, 0, stream>>>(norm, Wmsg, Wskip, Wt);
  k_convert<<<(NN * 64 + 255) / 256, 256, 0, stream>>>(feats, featsb);
  k_scan1<<<SB, 1024, 0, stream>>>(cnt, bsum);
  k_scan2<<<1, 64, 0, stream>>>(bsum);
  k_scan3<<<SB, 1024, 0, stream>>>(cnt, bsum, cursor);
  k_fill<<<(ET + 255) / 256, 256, 0, stream>>>(srcE, dstE, srcA, dstA, ef, Watt,
                                               batt, norm, cursor, rank16,
                                               recSC, recEF);
  k_pull_out<<<NN / 32, 256, 0, stream>>>(feats, featsb, cnt, cursor, norm,
                                          recSC, recEF, Wedge, bedge, Wt,
                                          bmsg, bskip, out);
}

// Round 5
// 542.713 us; speedup vs baseline: 6.9841x; 1.1415x over previous
//
#include <hip/hip_runtime.h>
#include <hip/hip_bf16.h>

#define NN 100000
#define NP 100096            // 782 * 128, padded row count for GEMM
#define EM 1600000
#define EA 200000
#define ET (EM + EA)
#define SB 98                // scan blocks of 1024: 98*1024 >= NN

// ws layout (4B units):
//  norm[NN] (deg in-place) | cnt[NN] int | cursor[NN] int | bsum[128] int |
//  Wb[16384] (bf16 [j=0..127][k=0..255] packed pairs) |
//  recSC[ET] uint | recEF[ET] uint2 | featsb[64*NP] | rstb[64*NP] | rank16[ET] ushort
// total = 3*NN + 128 + 16384 + 3*ET + 128*NP + ET/2 = 19,428,800 dwords = 77.7 MB
#define OFF_NORM 0
#define OFF_CNT  (NN)
#define OFF_CUR  (2*NN)
#define OFF_BSUM (3*NN)
#define OFF_WB   (3*NN + 128)
#define OFF_RSC  (3*NN + 128 + 16384)
#define OFF_REF  (OFF_RSC + ET)
#define OFF_FB   (OFF_REF + 2*ET)
#define OFF_RB   (OFF_FB + 64*NP)
#define OFF_RANK (OFF_RB + 64*NP)

#define UNP_LO(u) __uint_as_float((u) << 16)
#define UNP_HI(u) __uint_as_float((u) & 0xFFFF0000u)

typedef __attribute__((ext_vector_type(8))) short bf16x8;
typedef __attribute__((ext_vector_type(4))) float f32x4;

static __device__ __forceinline__ unsigned pack_bf16x2(float a, float b) {
  union { __hip_bfloat162 v; unsigned u; } cv;
  cv.v = __float22bfloat162_rn(make_float2(a, b));
  return cv.u;
}

// count degrees; save each edge's arrival rank within its dst bucket
__global__ __launch_bounds__(256) void k_count(
    const int* __restrict__ srcE, const int* __restrict__ dstE,
    const int* __restrict__ dstA,
    float* __restrict__ deg, int* __restrict__ cnt,
    unsigned short* __restrict__ rank16) {
  int e = blockIdx.x * 256 + threadIdx.x;
  if (e < EM) {
    unsafeAtomicAdd(&deg[srcE[e]], 1.0f);
    rank16[e] = (unsigned short)atomicAdd(&cnt[dstE[e]], 1);
  } else if (e < ET) {
    rank16[e] = (unsigned short)atomicAdd(&cnt[dstA[e - EM]], 1);
  }
}

// norm = rsqrt(deg) in place; build Wb bf16: Wb[j][k] = Wmsg[j][k] (k<128),
// Wskip[j][k-128] (k>=128); row pitch 128 uints (256 bf16)
__global__ __launch_bounds__(256) void k_norm_wt(
    float* __restrict__ norm,
    const float* __restrict__ Wmsg, const float* __restrict__ Wskip,
    unsigned* __restrict__ Wb) {
  int i = blockIdx.x * 256 + threadIdx.x;
  if (i < NN) {
    float dg = norm[i];
    norm[i] = dg > 0.0f ? rsqrtf(dg) : 0.0f;
  }
  if (i < 16384) {
    int j = i >> 7, kk = i & 127;   // kk = uint index within row (2 bf16)
    float a, b;
    if (kk < 64) {
      a = Wmsg[j * 128 + 2 * kk];
      b = Wmsg[j * 128 + 2 * kk + 1];
    } else {
      a = Wskip[j * 128 + 2 * kk - 128];
      b = Wskip[j * 128 + 2 * kk - 127];
    }
    Wb[j * 128 + kk] = pack_bf16x2(a, b);
  }
}

// feats -> bf16 pairs; zero the pad rows
__global__ __launch_bounds__(256) void k_convert(
    const float* __restrict__ feats, unsigned* __restrict__ featsb) {
  int i = blockIdx.x * 256 + threadIdx.x;
  if (i >= NP * 64) return;
  if (i < NN * 64) {
    float2 f = ((const float2*)feats)[i];
    featsb[i] = pack_bf16x2(f.x, f.y);
  } else {
    featsb[i] = 0u;
  }
}

__global__ __launch_bounds__(1024) void k_scan1(const int* __restrict__ cnt,
                                                int* __restrict__ bsum) {
  __shared__ int ws16[16];
  int tid = threadIdx.x, lane = tid & 63, wid = tid >> 6;
  int i = blockIdx.x * 1024 + tid;
  int v = (i < NN) ? cnt[i] : 0;
#pragma unroll
  for (int s = 1; s < 64; s <<= 1) v += __shfl_xor(v, s, 64);
  if (lane == 0) ws16[wid] = v;
  __syncthreads();
  if (tid == 0) {
    int a = 0;
#pragma unroll
    for (int w = 0; w < 16; ++w) a += ws16[w];
    bsum[blockIdx.x] = a;
  }
}

__global__ __launch_bounds__(64) void k_scan2(int* __restrict__ bsum) {
  int lane = threadIdx.x;
  int v0 = (lane < SB) ? bsum[lane] : 0;
  int v1 = (64 + lane < SB) ? bsum[64 + lane] : 0;
  int x0 = v0, x1 = v1;
#pragma unroll
  for (int s = 1; s < 64; s <<= 1) {
    int y = __shfl_up(x0, s, 64); if (lane >= s) x0 += y;
  }
#pragma unroll
  for (int s = 1; s < 64; s <<= 1) {
    int y = __shfl_up(x1, s, 64); if (lane >= s) x1 += y;
  }
  int t0 = __shfl(x0, 63, 64);
  if (lane < SB) bsum[lane] = x0 - v0;
  if (64 + lane < SB) bsum[64 + lane] = t0 + x1 - v1;
}

__global__ __launch_bounds__(1024) void k_scan3(const int* __restrict__ cnt,
                                                const int* __restrict__ bsum,
                                                int* __restrict__ cursor) {
  __shared__ int ws16[16];
  int tid = threadIdx.x, lane = tid & 63, wid = tid >> 6;
  int i = blockIdx.x * 1024 + tid;
  int v = (i < NN) ? cnt[i] : 0;
  int x = v;
#pragma unroll
  for (int s = 1; s < 64; s <<= 1) {
    int y = __shfl_up(x, s, 64); if (lane >= s) x += y;
  }
  if (lane == 63) ws16[wid] = x;
  __syncthreads();
  if (tid == 0) {
    int a = bsum[blockIdx.x];
#pragma unroll
    for (int w = 0; w < 16; ++w) { int t = ws16[w]; ws16[w] = a; a += t; }
  }
  __syncthreads();
  if (i < NN) cursor[i] = ws16[wid] + x - v;   // exclusive start of bucket
}

// bucket by dst, atomic-free: slot = cursor[d] + rank16[e]
__global__ __launch_bounds__(256) void k_fill(
    const int* __restrict__ srcE, const int* __restrict__ dstE,
    const int* __restrict__ srcA, const int* __restrict__ dstA,
    const float* __restrict__ ef, const float* __restrict__ Watt,
    const float* __restrict__ batt, const float* __restrict__ norm,
    const int* __restrict__ cursor, const unsigned short* __restrict__ rank16,
    unsigned* __restrict__ recSC, uint2* __restrict__ recEF) {
  int e = blockIdx.x * 256 + threadIdx.x;
  if (e >= ET) return;
  int s, d;
  float att;
  float4 f;
  if (e < EM) {
    s = srcE[e]; d = dstE[e];
    f = ((const float4*)ef)[e];
    float z = f.x * Watt[0] + f.y * Watt[1] + f.z * Watt[2] + f.w * Watt[3] + batt[0];
    att = 1.0f / (1.0f + __expf(-z));
  } else {
    int ea = e - EM;
    s = srcA[ea]; d = dstA[ea];
    f = make_float4(0.f, 0.f, 0.f, 0.f);
    att = 1.0f / (1.0f + __expf(-batt[0]));
  }
  float c = att * norm[s];
  unsigned q = (unsigned)(c * 32767.0f + 0.5f);
  if (q > 32767u) q = 32767u;
  int slot = cursor[d] + (int)rank16[e];
  recSC[slot] = ((unsigned)s << 15) | q;
  recEF[slot] = make_uint2(pack_bf16x2(f.x, f.y), pack_bf16x2(f.z, f.w));
}

// Pull only: 1 wave per node, no LDS, no barriers -> 32 waves/CU for latency
// hiding. Writes rst row as packed bf16 (rstb).
__global__ __launch_bounds__(256) void k_pull(
    const float* __restrict__ feats, const unsigned* __restrict__ featsb,
    const int* __restrict__ cnt, const int* __restrict__ cursor,
    const float* __restrict__ norm, const unsigned* __restrict__ recSC,
    const uint2* __restrict__ recEF,
    const float* __restrict__ Wedge, const float* __restrict__ bedge,
    unsigned* __restrict__ rstb) {
  int lane = threadIdx.x & 63, wid = threadIdx.x >> 6;
  int n = blockIdx.x * 4 + wid;
  if (n >= NP) return;
  if (n >= NN) { rstb[n * 64 + lane] = 0u; return; }

  int beg = __builtin_amdgcn_readfirstlane(cursor[n]);
  int len = __builtin_amdgcn_readfirstlane(cnt[n]);
  int end = beg + len;
  float2 acc = make_float2(0.f, 0.f);
  int e = beg;
  for (; e + 8 <= end; e += 8) {
    unsigned r0 = recSC[e+0], r1 = recSC[e+1], r2 = recSC[e+2], r3 = recSC[e+3];
    unsigned r4 = recSC[e+4], r5 = recSC[e+5], r6 = recSC[e+6], r7 = recSC[e+7];
    unsigned u0 = featsb[(r0 >> 15) * 64 + lane];
    unsigned u1 = featsb[(r1 >> 15) * 64 + lane];
    unsigned u2 = featsb[(r2 >> 15) * 64 + lane];
    unsigned u3 = featsb[(r3 >> 15) * 64 + lane];
    unsigned u4 = featsb[(r4 >> 15) * 64 + lane];
    unsigned u5 = featsb[(r5 >> 15) * 64 + lane];
    unsigned u6 = featsb[(r6 >> 15) * 64 + lane];
    unsigned u7 = featsb[(r7 >> 15) * 64 + lane];
    float c0 = (float)(r0 & 32767u) * (1.0f / 32767.0f);
    float c1 = (float)(r1 & 32767u) * (1.0f / 32767.0f);
    float c2 = (float)(r2 & 32767u) * (1.0f / 32767.0f);
    float c3 = (float)(r3 & 32767u) * (1.0f / 32767.0f);
    float c4 = (float)(r4 & 32767u) * (1.0f / 32767.0f);
    float c5 = (float)(r5 & 32767u) * (1.0f / 32767.0f);
    float c6 = (float)(r6 & 32767u) * (1.0f / 32767.0f);
    float c7 = (float)(r7 & 32767u) * (1.0f / 32767.0f);
    acc.x += c0 * UNP_LO(u0) + c1 * UNP_LO(u1) + c2 * UNP_LO(u2) + c3 * UNP_LO(u3)
           + c4 * UNP_LO(u4) + c5 * UNP_LO(u5) + c6 * UNP_LO(u6) + c7 * UNP_LO(u7);
    acc.y += c0 * UNP_HI(u0) + c1 * UNP_HI(u1) + c2 * UNP_HI(u2) + c3 * UNP_HI(u3)
           + c4 * UNP_HI(u4) + c5 * UNP_HI(u5) + c6 * UNP_HI(u6) + c7 * UNP_HI(u7);
  }
  for (; e < end; ++e) {
    unsigned r = recSC[e];
    unsigned u = featsb[(r >> 15) * 64 + lane];
    float c = (float)(r & 32767u) * (1.0f / 32767.0f);
    acc.x += c * UNP_LO(u);
    acc.y += c * UNP_HI(u);
  }
  // lane-parallel ef sum over the bucket, butterfly all-reduce
  float4 efa = make_float4(0.f, 0.f, 0.f, 0.f);
  for (int b = beg + lane; b < end; b += 64) {
    uint2 g = recEF[b];
    efa.x += UNP_LO(g.x); efa.y += UNP_HI(g.x);
    efa.z += UNP_LO(g.y); efa.w += UNP_HI(g.y);
  }
#pragma unroll
  for (int s = 1; s < 64; s <<= 1) {
    efa.x += __shfl_xor(efa.x, s, 64);
    efa.y += __shfl_xor(efa.y, s, 64);
    efa.z += __shfl_xor(efa.z, s, 64);
    efa.w += __shfl_xor(efa.w, s, 64);
  }
  float flen = (float)len;
  float nm = norm[n];
  float2 f = ((const float2*)feats)[n * 64 + lane];
  float4 wa = ((const float4*)Wedge)[2 * lane + 0];
  float4 wb = ((const float4*)Wedge)[2 * lane + 1];
  float2 be = ((const float2*)bedge)[lane];
  float tx = wa.x * efa.x + wa.y * efa.y + wa.z * efa.z + wa.w * efa.w;
  float ty = wb.x * efa.x + wb.y * efa.y + wb.z * efa.z + wb.w * efa.w;
  float rx = (acc.x + tx + flen * (be.x + nm * f.x)) * nm;
  float ry = (acc.y + ty + flen * (be.y + nm * f.y)) * nm;
  rstb[n * 64 + lane] = pack_bf16x2(rx, ry);
}

// MFMA GEMM: out[NN][128] = [rstb | featsb](bf16) @ Wb^T-ish + bias.
// Block 256 thr = 4 waves; block covers 128 rows; wave covers 32 rows x 128 cols.
// 16x16x32 bf16 MFMA. A: m=lane&15, k=quad*8+j. B: n=lane&15, k=quad*8+j.
// D: col=lane&15, row=quad*4+reg.
__global__ __launch_bounds__(256) void k_gemm(
    const unsigned* __restrict__ rstb, const unsigned* __restrict__ featsb,
    const unsigned* __restrict__ Wb,
    const float* __restrict__ bmsg, const float* __restrict__ bskip,
    float* __restrict__ out) {
  int lane = threadIdx.x & 63, wid = threadIdx.x >> 6;
  int quad = lane >> 4, l15 = lane & 15;
  int rowt = blockIdx.x * 128 + wid * 32;
  int m0 = rowt + l15;
  int m1 = m0 + 16;

  f32x4 acc0[8], acc1[8];
#pragma unroll
  for (int ct = 0; ct < 8; ++ct) {
    acc0[ct] = (f32x4){0.f, 0.f, 0.f, 0.f};
    acc1[ct] = (f32x4){0.f, 0.f, 0.f, 0.f};
  }

#pragma unroll
  for (int ks = 0; ks < 8; ++ks) {
    int kb = ks * 32;
    const unsigned* Xsrc = (kb < 128) ? rstb : featsb;
    int off = ((kb & 127) >> 1) + quad * 4;    // dword offset in 64-dword row
    bf16x8 a0 = *(const bf16x8*)(Xsrc + m0 * 64 + off);
    bf16x8 a1 = *(const bf16x8*)(Xsrc + m1 * 64 + off);
#pragma unroll
    for (int ct = 0; ct < 8; ++ct) {
      int j = ct * 16 + l15;
      bf16x8 b = *(const bf16x8*)(Wb + j * 128 + (kb >> 1) + quad * 4);
      acc0[ct] = __builtin_amdgcn_mfma_f32_16x16x32_bf16(a0, b, acc0[ct], 0, 0, 0);
      acc1[ct] = __builtin_amdgcn_mfma_f32_16x16x32_bf16(a1, b, acc1[ct], 0, 0, 0);
    }
  }

#pragma unroll
  for (int ct = 0; ct < 8; ++ct) {
    int col = ct * 16 + l15;
    float bia = bmsg[col] + bskip[col];
#pragma unroll
    for (int r = 0; r < 4; ++r) {
      int row0 = rowt + quad * 4 + r;
      if (row0 < NN) out[row0 * 128 + col] = acc0[ct][r] + bia;
      int row1 = row0 + 16;
      if (row1 < NN) out[row1 * 128 + col] = acc1[ct][r] + bia;
    }
  }
}

extern "C" void kernel_launch(void* const* d_in, const int* in_sizes, int n_in,
                              void* d_out, int out_size, void* d_ws, size_t ws_size,
                              hipStream_t stream) {
  const float* feats  = (const float*)d_in[0];
  const float* ef     = (const float*)d_in[1];
  const int*   srcE   = (const int*)d_in[2];
  const int*   dstE   = (const int*)d_in[3];
  const int*   srcA   = (const int*)d_in[4];
  const int*   dstA   = (const int*)d_in[5];
  const float* Wskip  = (const float*)d_in[6];
  const float* bskip  = (const float*)d_in[7];
  const float* Wmsg   = (const float*)d_in[8];
  const float* bmsg   = (const float*)d_in[9];
  const float* Wedge  = (const float*)d_in[10];
  const float* bedge  = (const float*)d_in[11];
  const float* Watt   = (const float*)d_in[12];
  const float* batt   = (const float*)d_in[13];
  float* out = (float*)d_out;
  float* ws  = (float*)d_ws;

  float*          norm   = ws + OFF_NORM;
  int*            cnt    = (int*)(ws + OFF_CNT);
  int*            cursor = (int*)(ws + OFF_CUR);
  int*            bsum   = (int*)(ws + OFF_BSUM);
  unsigned*       Wb     = (unsigned*)(ws + OFF_WB);
  unsigned*       recSC  = (unsigned*)(ws + OFF_RSC);
  uint2*          recEF  = (uint2*)(ws + OFF_REF);
  unsigned*       featsb = (unsigned*)(ws + OFF_FB);
  unsigned*       rstb   = (unsigned*)(ws + OFF_RB);
  unsigned short* rank16 = (unsigned short*)(ws + OFF_RANK);

  hipMemsetAsync(ws, 0, (size_t)(2 * NN) * sizeof(float), stream);  // deg + cnt

  k_count<<<(ET + 255) / 256, 256, 0, stream>>>(srcE, dstE, dstA, norm, cnt, rank16);
  k_norm_wt<<<(NN + 255) / 256, 256, 0, stream>>>(norm, Wmsg, Wskip, Wb);
  k_convert<<<(NP * 64 + 255) / 256, 256, 0, stream>>>(feats, featsb);
  k_scan1<<<SB, 1024, 0, stream>>>(cnt, bsum);
  k_scan2<<<1, 64, 0, stream>>>(bsum);
  k_scan3<<<SB, 1024, 0, stream>>>(cnt, bsum, cursor);
  k_fill<<<(ET + 255) / 256, 256, 0, stream>>>(srcE, dstE, srcA, dstA, ef, Watt,
                                               batt, norm, cursor, rank16,
                                               recSC, recEF);
  k_pull<<<NP / 4, 256, 0, stream>>>(feats, featsb, cnt, cursor, norm,
                                     recSC, recEF, Wedge, bedge, rstb);
  k_gemm<<<NP / 128, 256, 0, stream>>>(rstb, featsb, Wb, bmsg, bskip, out);
}